// Round 1
// baseline (302.848 us; speedup 1.0000x reference)
//
#include <hip/hip_runtime.h>

// DistNet: out[n] = sigmoid((min_p ||x_n - p||^2 + alpha) / beta)
// beta = softplus(beta_raw), alpha = -beta*ln(1000)
// x: [65536,128] f32, points: [2048,128] f32, beta_raw: [1] f32, out: [65536] f32

#define NROWS 65536
#define NPTS  2048
#define DIMS  128
#define LOG1000F 6.9077542789816375f

typedef __attribute__((ext_vector_type(8))) __bf16 bf16x8;
typedef __attribute__((ext_vector_type(8))) unsigned short ushort8;
typedef __attribute__((ext_vector_type(4))) float f32x4;

union BfCast { ushort8 u; bf16x8 b; };

__device__ inline unsigned short f2bf(float f) {
    // round-to-nearest-even truncation f32 -> bf16 (inputs are finite gaussians)
    unsigned int u = __float_as_uint(f);
    u += 0x7FFFu + ((u >> 16) & 1u);
    return (unsigned short)(u >> 16);
}

// --- pre-kernel: points f32 -> bf16 in ws, plus ||p||^2 ---------------------
__global__ __launch_bounds__(256) void prep_points_kernel(
    const float* __restrict__ pts, unsigned short* __restrict__ ptsbf,
    float* __restrict__ pnorm)
{
    int tid  = threadIdx.x;
    int lane = tid & 63;
    int w    = tid >> 6;
    int pt   = blockIdx.x * 4 + w;            // one wave per point
    const float2 v = *reinterpret_cast<const float2*>(
        pts + (size_t)pt * DIMS + lane * 2);  // 2 features per lane
    ushort2 b;
    b.x = f2bf(v.x);
    b.y = f2bf(v.y);
    *reinterpret_cast<ushort2*>(ptsbf + (size_t)pt * DIMS + lane * 2) = b;
    float ss = v.x * v.x + v.y * v.y;
    ss += __shfl_xor(ss, 1, 64);
    ss += __shfl_xor(ss, 2, 64);
    ss += __shfl_xor(ss, 4, 64);
    ss += __shfl_xor(ss, 8, 64);
    ss += __shfl_xor(ss, 16, 64);
    ss += __shfl_xor(ss, 32, 64);
    if (lane == 0) pnorm[pt] = ss;
}

// --- main kernel: MFMA x.p^T, min over points, sigmoid ----------------------
// grid: NROWS/64 blocks of 256 threads (4 waves); each wave owns 16 rows.
__global__ __launch_bounds__(256) void distnet_main_kernel(
    const float* __restrict__ x, const unsigned short* __restrict__ ptsbf,
    const float* __restrict__ pnorm, const float* __restrict__ beta_raw,
    float* __restrict__ out)
{
    __shared__ float s_pn[NPTS];   // 8 KB: ||p||^2 for all points
    __shared__ float s_xn[64];     // per-block row norms

    int tid = threadIdx.x;
    for (int i = tid; i < NPTS; i += 256) s_pn[i] = pnorm[i];

    int wave = tid >> 6;
    int lane = tid & 63;
    int m    = lane & 15;          // A-fragment row / B-fragment col index
    int q    = lane >> 4;          // k-group (quad)
    int r0   = blockIdx.x * 64 + wave * 16;
    int row  = r0 + m;

    // Load A fragments (16 rows x 128 k, bf16) + accumulate ||x||^2 in f32.
    // A layout for mfma_f32_16x16x32_bf16: lane holds A[m=lane&15][k=q*8+j].
    bf16x8 afrag[4];
    float sumsq = 0.f;
    const float* xrow = x + (size_t)row * DIMS + q * 8;
#pragma unroll
    for (int c = 0; c < 4; ++c) {
        float4 v0 = *reinterpret_cast<const float4*>(xrow + c * 32);
        float4 v1 = *reinterpret_cast<const float4*>(xrow + c * 32 + 4);
        BfCast cv;
        cv.u[0] = f2bf(v0.x); cv.u[1] = f2bf(v0.y);
        cv.u[2] = f2bf(v0.z); cv.u[3] = f2bf(v0.w);
        cv.u[4] = f2bf(v1.x); cv.u[5] = f2bf(v1.y);
        cv.u[6] = f2bf(v1.z); cv.u[7] = f2bf(v1.w);
        afrag[c] = cv.b;
        sumsq += v0.x * v0.x + v0.y * v0.y + v0.z * v0.z + v0.w * v0.w;
        sumsq += v1.x * v1.x + v1.y * v1.y + v1.z * v1.z + v1.w * v1.w;
    }
    // each lane has 32 of its row's 128 features; combine across the 4 quads
    sumsq += __shfl_xor(sumsq, 16, 64);
    sumsq += __shfl_xor(sumsq, 32, 64);
    if (lane < 16) s_xn[wave * 16 + lane] = sumsq;  // lane==m here
    __syncthreads();

    // C/D layout: col = lane&15 (point), row = q*4 + reg
    float xn[4];
#pragma unroll
    for (int r = 0; r < 4; ++r) xn[r] = s_xn[wave * 16 + q * 4 + r];

    float runmin[4] = {1e30f, 1e30f, 1e30f, 1e30f};

    for (int pt = 0; pt < NPTS / 16; ++pt) {
        // B layout: lane holds B[n=lane&15][k=q*8+j]; points are [n][k] row-major
        const unsigned short* bbase =
            ptsbf + (size_t)(pt * 16 + m) * DIMS + q * 8;
        f32x4 acc = {0.f, 0.f, 0.f, 0.f};
#pragma unroll
        for (int c = 0; c < 4; ++c) {
            ushort8 braw = *reinterpret_cast<const ushort8*>(bbase + c * 32);
            BfCast cv; cv.u = braw;
            acc = __builtin_amdgcn_mfma_f32_16x16x32_bf16(afrag[c], cv.b, acc,
                                                          0, 0, 0);
        }
        float pn = s_pn[pt * 16 + m];
#pragma unroll
        for (int r = 0; r < 4; ++r) {
            float d2 = fmaf(-2.f, acc[r], xn[r] + pn);
            d2 = fmaxf(d2, 0.f);
            runmin[r] = fminf(runmin[r], d2);
        }
    }

    // reduce min across the 16 cols held by lanes sharing the same quad q
    float br    = beta_raw[0];
    float beta  = log1pf(expf(br));
    float alpha = -beta * LOG1000F;
#pragma unroll
    for (int r = 0; r < 4; ++r) {
        float v = runmin[r];
        v = fminf(v, __shfl_xor(v, 1, 64));
        v = fminf(v, __shfl_xor(v, 2, 64));
        v = fminf(v, __shfl_xor(v, 4, 64));
        v = fminf(v, __shfl_xor(v, 8, 64));
        if (m == 0) {
            float z = (v + alpha) / beta;
            out[r0 + q * 4 + r] = 1.f / (1.f + expf(-z));
        }
    }
}

extern "C" void kernel_launch(void* const* d_in, const int* in_sizes, int n_in,
                              void* d_out, int out_size, void* d_ws, size_t ws_size,
                              hipStream_t stream) {
    const float* x        = (const float*)d_in[0];
    const float* pts      = (const float*)d_in[1];
    const float* beta_raw = (const float*)d_in[2];
    float* out            = (float*)d_out;

    unsigned short* ptsbf = (unsigned short*)d_ws;                 // 512 KB
    float* pnorm = (float*)((char*)d_ws + (size_t)NPTS * DIMS * 2); // 8 KB

    prep_points_kernel<<<NPTS / 4, 256, 0, stream>>>(pts, ptsbf, pnorm);
    distnet_main_kernel<<<NROWS / 64, 256, 0, stream>>>(x, ptsbf, pnorm,
                                                        beta_raw, out);
}

// Round 2
// 191.989 us; speedup vs baseline: 1.5774x; 1.5774x over previous
//
#include <hip/hip_runtime.h>

// DistNet: out[n] = sigmoid((min_p ||x_n - p||^2 + alpha) / beta)
// beta = softplus(beta_raw), alpha = -beta*ln(1000)
// x: [65536,128] f32, points: [2048,128] f32, beta_raw: [1] f32, out: [65536] f32
//
// R2 design: 32 rows/wave (2x 16-row MFMA tiles), register double-buffered B
// prefetch, min(pn - 2*x.p) epilogue with ||x||^2 + clip folded to the end.

#define NROWS 65536
#define NPTS  2048
#define DIMS  128
#define LOG1000F 6.9077542789816375f

typedef __attribute__((ext_vector_type(8))) __bf16 bf16x8;
typedef __attribute__((ext_vector_type(8))) unsigned short ushort8;
typedef __attribute__((ext_vector_type(4))) float f32x4;

union BfCast { ushort8 u; bf16x8 b; };

__device__ inline unsigned short f2bf(float f) {
    unsigned int u = __float_as_uint(f);
    u += 0x7FFFu + ((u >> 16) & 1u);
    return (unsigned short)(u >> 16);
}

// --- pre-kernel: points f32 -> bf16 in ws, plus ||p||^2 ---------------------
__global__ __launch_bounds__(256) void prep_points_kernel(
    const float* __restrict__ pts, unsigned short* __restrict__ ptsbf,
    float* __restrict__ pnorm)
{
    int tid  = threadIdx.x;
    int lane = tid & 63;
    int w    = tid >> 6;
    int pt   = blockIdx.x * 4 + w;            // one wave per point
    const float2 v = *reinterpret_cast<const float2*>(
        pts + (size_t)pt * DIMS + lane * 2);  // 2 features per lane
    ushort2 b;
    b.x = f2bf(v.x);
    b.y = f2bf(v.y);
    *reinterpret_cast<ushort2*>(ptsbf + (size_t)pt * DIMS + lane * 2) = b;
    float ss = v.x * v.x + v.y * v.y;
    ss += __shfl_xor(ss, 1, 64);
    ss += __shfl_xor(ss, 2, 64);
    ss += __shfl_xor(ss, 4, 64);
    ss += __shfl_xor(ss, 8, 64);
    ss += __shfl_xor(ss, 16, 64);
    ss += __shfl_xor(ss, 32, 64);
    if (lane == 0) pnorm[pt] = ss;
}

// --- main kernel ------------------------------------------------------------
// grid: NROWS/128 = 512 blocks x 256 threads (4 waves); wave owns 32 rows.
__global__ __launch_bounds__(256, 2) void distnet_main_kernel(
    const float* __restrict__ x, const unsigned short* __restrict__ ptsbf,
    const float* __restrict__ pnorm, const float* __restrict__ beta_raw,
    float* __restrict__ out)
{
    __shared__ float s_pn[NPTS];   // 8 KB: ||p||^2 for all points
    __shared__ float s_xn[128];    // per-block row norms (4 waves x 32 rows)

    int tid = threadIdx.x;
    for (int i = tid; i < NPTS; i += 256) s_pn[i] = pnorm[i];

    int wave = tid >> 6;
    int lane = tid & 63;
    int m    = lane & 15;          // A row / B col (point) index
    int q    = lane >> 4;          // k-quad
    int r0   = blockIdx.x * 128 + wave * 32;

    // A fragments: 2 tiles x 4 k-chunks. Lane holds A[m][k=q*8+j] per chunk.
    bf16x8 afrag[2][4];
#pragma unroll
    for (int t = 0; t < 2; ++t) {
        const float* xrow = x + (size_t)(r0 + t * 16 + m) * DIMS + q * 8;
        float sumsq = 0.f;
#pragma unroll
        for (int c = 0; c < 4; ++c) {
            float4 v0 = *reinterpret_cast<const float4*>(xrow + c * 32);
            float4 v1 = *reinterpret_cast<const float4*>(xrow + c * 32 + 4);
            BfCast cv;
            cv.u[0] = f2bf(v0.x); cv.u[1] = f2bf(v0.y);
            cv.u[2] = f2bf(v0.z); cv.u[3] = f2bf(v0.w);
            cv.u[4] = f2bf(v1.x); cv.u[5] = f2bf(v1.y);
            cv.u[6] = f2bf(v1.z); cv.u[7] = f2bf(v1.w);
            afrag[t][c] = cv.b;
            sumsq += v0.x * v0.x + v0.y * v0.y + v0.z * v0.z + v0.w * v0.w;
            sumsq += v1.x * v1.x + v1.y * v1.y + v1.z * v1.z + v1.w * v1.w;
        }
        sumsq += __shfl_xor(sumsq, 16, 64);
        sumsq += __shfl_xor(sumsq, 32, 64);
        if (lane < 16) s_xn[wave * 32 + t * 16 + lane] = sumsq;
    }
    __syncthreads();

    // runmin tracks min_p (||p||^2 - 2 x.p); ||x||^2 + clip folded in at end.
    float runmin[2][4] = {{1e30f, 1e30f, 1e30f, 1e30f},
                          {1e30f, 1e30f, 1e30f, 1e30f}};

    const unsigned short* bb0 = ptsbf + (size_t)m * DIMS + q * 8;

    ushort8 b0[4], b1[4];
#pragma unroll
    for (int c = 0; c < 4; ++c)
        b0[c] = *reinterpret_cast<const ushort8*>(bb0 + c * 32);

    for (int pt = 0; pt < NPTS / 16; pt += 2) {
        // prefetch tile pt+1 while computing tile pt
        const unsigned short* bb1 = bb0 + (size_t)16 * DIMS;
#pragma unroll
        for (int c = 0; c < 4; ++c)
            b1[c] = *reinterpret_cast<const ushort8*>(bb1 + c * 32);

        {
            float pn = s_pn[pt * 16 + m];
            f32x4 acc0 = {0.f, 0.f, 0.f, 0.f};
            f32x4 acc1 = {0.f, 0.f, 0.f, 0.f};
#pragma unroll
            for (int c = 0; c < 4; ++c) {
                BfCast cv; cv.u = b0[c];
                acc0 = __builtin_amdgcn_mfma_f32_16x16x32_bf16(afrag[0][c], cv.b, acc0, 0, 0, 0);
                acc1 = __builtin_amdgcn_mfma_f32_16x16x32_bf16(afrag[1][c], cv.b, acc1, 0, 0, 0);
            }
#pragma unroll
            for (int r = 0; r < 4; ++r) {
                runmin[0][r] = fminf(runmin[0][r], fmaf(-2.f, acc0[r], pn));
                runmin[1][r] = fminf(runmin[1][r], fmaf(-2.f, acc1[r], pn));
            }
        }

        // prefetch tile pt+2 (clamped) while computing tile pt+1
        const unsigned short* bb2 =
            bb0 + (size_t)((pt + 2 < NPTS / 16) ? 32 : 16) * DIMS;
#pragma unroll
        for (int c = 0; c < 4; ++c)
            b0[c] = *reinterpret_cast<const ushort8*>(bb2 + c * 32);

        {
            float pn = s_pn[(pt + 1) * 16 + m];
            f32x4 acc0 = {0.f, 0.f, 0.f, 0.f};
            f32x4 acc1 = {0.f, 0.f, 0.f, 0.f};
#pragma unroll
            for (int c = 0; c < 4; ++c) {
                BfCast cv; cv.u = b1[c];
                acc0 = __builtin_amdgcn_mfma_f32_16x16x32_bf16(afrag[0][c], cv.b, acc0, 0, 0, 0);
                acc1 = __builtin_amdgcn_mfma_f32_16x16x32_bf16(afrag[1][c], cv.b, acc1, 0, 0, 0);
            }
#pragma unroll
            for (int r = 0; r < 4; ++r) {
                runmin[0][r] = fminf(runmin[0][r], fmaf(-2.f, acc0[r], pn));
                runmin[1][r] = fminf(runmin[1][r], fmaf(-2.f, acc1[r], pn));
            }
        }

        bb0 += (size_t)32 * DIMS;
    }

    // C/D layout: col = m, row_local = q*4 + r. Reduce min over the 16 cols.
    float br    = beta_raw[0];
    float beta  = log1pf(expf(br));
    float alpha = -beta * LOG1000F;
#pragma unroll
    for (int t = 0; t < 2; ++t) {
#pragma unroll
        for (int r = 0; r < 4; ++r) {
            float v = runmin[t][r];
            v = fminf(v, __shfl_xor(v, 1, 64));
            v = fminf(v, __shfl_xor(v, 2, 64));
            v = fminf(v, __shfl_xor(v, 4, 64));
            v = fminf(v, __shfl_xor(v, 8, 64));
            if (m == 0) {
                float xnv = s_xn[wave * 32 + t * 16 + q * 4 + r];
                float d2  = fmaxf(xnv + v, 0.f);
                float z   = (d2 + alpha) / beta;
                out[r0 + t * 16 + q * 4 + r] = 1.f / (1.f + expf(-z));
            }
        }
    }
}

extern "C" void kernel_launch(void* const* d_in, const int* in_sizes, int n_in,
                              void* d_out, int out_size, void* d_ws, size_t ws_size,
                              hipStream_t stream) {
    const float* x        = (const float*)d_in[0];
    const float* pts      = (const float*)d_in[1];
    const float* beta_raw = (const float*)d_in[2];
    float* out            = (float*)d_out;

    unsigned short* ptsbf = (unsigned short*)d_ws;                  // 512 KB
    float* pnorm = (float*)((char*)d_ws + (size_t)NPTS * DIMS * 2); // 8 KB

    prep_points_kernel<<<NPTS / 4, 256, 0, stream>>>(pts, ptsbf, pnorm);
    distnet_main_kernel<<<NROWS / 128, 256, 0, stream>>>(x, ptsbf, pnorm,
                                                         beta_raw, out);
}

// Round 3
// 117.900 us; speedup vs baseline: 2.5687x; 1.6284x over previous
//
#include <hip/hip_runtime.h>

// DistNet: out[n] = sigmoid((min_p ||x_n - p||^2 + alpha) / beta)
// beta = softplus(beta_raw), alpha = -beta*ln(1000)
// x: [65536,128] f32, points: [2048,128] f32, beta_raw: [1] f32, out: [65536] f32
//
// R3 design: async global_load_lds (16B) double-buffered staging of 64-point
// tiles into LDS in MFMA-fragment order (conflict-free ds_read_b128), shared
// across the block's 4 waves. 32 rows/wave. min(pn - 2*x.p) epilogue.

#define NROWS 65536
#define NPTS  2048
#define DIMS  128
#define LOG1000F 6.9077542789816375f
#define STAGE_PTS 64
#define NSTAGES (NPTS / STAGE_PTS)   // 32

typedef __attribute__((ext_vector_type(8))) __bf16 bf16x8;
typedef __attribute__((ext_vector_type(8))) unsigned short ushort8;
typedef __attribute__((ext_vector_type(4))) float f32x4;

union BfCast { ushort8 u; bf16x8 b; };

__device__ inline unsigned short f2bf(float f) {
    unsigned int u = __float_as_uint(f);
    u += 0x7FFFu + ((u >> 16) & 1u);
    return (unsigned short)(u >> 16);
}

// --- pre-kernel: points f32 -> bf16 in ws, plus ||p||^2 ---------------------
__global__ __launch_bounds__(256) void prep_points_kernel(
    const float* __restrict__ pts, unsigned short* __restrict__ ptsbf,
    float* __restrict__ pnorm)
{
    int tid  = threadIdx.x;
    int lane = tid & 63;
    int w    = tid >> 6;
    int pt   = blockIdx.x * 4 + w;            // one wave per point
    const float2 v = *reinterpret_cast<const float2*>(
        pts + (size_t)pt * DIMS + lane * 2);  // 2 features per lane
    ushort2 b;
    b.x = f2bf(v.x);
    b.y = f2bf(v.y);
    *reinterpret_cast<ushort2*>(ptsbf + (size_t)pt * DIMS + lane * 2) = b;
    float ss = v.x * v.x + v.y * v.y;
    ss += __shfl_xor(ss, 1, 64);
    ss += __shfl_xor(ss, 2, 64);
    ss += __shfl_xor(ss, 4, 64);
    ss += __shfl_xor(ss, 8, 64);
    ss += __shfl_xor(ss, 16, 64);
    ss += __shfl_xor(ss, 32, 64);
    if (lane == 0) pnorm[pt] = ss;
}

// --- main kernel ------------------------------------------------------------
// grid: NROWS/128 = 512 blocks x 256 threads (4 waves); wave owns 32 rows.
__global__ __launch_bounds__(256, 2) void distnet_main_kernel(
    const float* __restrict__ x, const unsigned short* __restrict__ ptsbf,
    const float* __restrict__ pnorm, const float* __restrict__ beta_raw,
    float* __restrict__ out)
{
    __shared__ float s_pn[NPTS];     // 8 KB: ||p||^2 for all points
    __shared__ float s_xn[128];      // per-block row norms
    // B stage buffers, fragment order: [buf][ (tile*4+chunk)*64 + lane ] x 16B
    __shared__ ushort8 s_b[2][STAGE_PTS * DIMS / 8];   // 2 x 16 KB

    int tid = threadIdx.x;
    for (int i = tid; i < NPTS; i += 256) s_pn[i] = pnorm[i];

    int wave = tid >> 6;
    int lane = tid & 63;
    int m    = lane & 15;          // A row / B col (point) index
    int q    = lane >> 4;          // k-quad
    int r0   = blockIdx.x * 128 + wave * 32;

    // A fragments: 2 row-tiles x 4 k-chunks; lane holds A[m][k=q*8+j].
    bf16x8 afrag[2][4];
#pragma unroll
    for (int t = 0; t < 2; ++t) {
        const float* xrow = x + (size_t)(r0 + t * 16 + m) * DIMS + q * 8;
        float sumsq = 0.f;
#pragma unroll
        for (int c = 0; c < 4; ++c) {
            float4 v0 = *reinterpret_cast<const float4*>(xrow + c * 32);
            float4 v1 = *reinterpret_cast<const float4*>(xrow + c * 32 + 4);
            BfCast cv;
            cv.u[0] = f2bf(v0.x); cv.u[1] = f2bf(v0.y);
            cv.u[2] = f2bf(v0.z); cv.u[3] = f2bf(v0.w);
            cv.u[4] = f2bf(v1.x); cv.u[5] = f2bf(v1.y);
            cv.u[6] = f2bf(v1.z); cv.u[7] = f2bf(v1.w);
            afrag[t][c] = cv.b;
            sumsq += v0.x * v0.x + v0.y * v0.y + v0.z * v0.z + v0.w * v0.w;
            sumsq += v1.x * v1.x + v1.y * v1.y + v1.z * v1.z + v1.w * v1.w;
        }
        sumsq += __shfl_xor(sumsq, 16, 64);
        sumsq += __shfl_xor(sumsq, 32, 64);
        if (lane < 16) s_xn[wave * 32 + t * 16 + lane] = sumsq;
    }

    // Async stage issue: wave w stages tile t=w (16 pts), chunks c=0..3.
    // Lane's global source: point p = s*64 + w*16 + m, k = c*32 + q*8.
    // LDS dest: wave-uniform base &s_b[buf][(w*4+c)*64], +lane*16 implicit.
    const unsigned char* gbase = (const unsigned char*)ptsbf;
    auto issue_stage = [&](int s, int buf) {
        size_t pbyte = (size_t)(s * STAGE_PTS + wave * 16 + m) * (DIMS * 2)
                       + (size_t)q * 16;
#pragma unroll
        for (int c = 0; c < 4; ++c) {
            const void* g = gbase + pbyte + c * 64;
            void* l = (void*)&s_b[buf][(wave * 4 + c) * 64];
            __builtin_amdgcn_global_load_lds(
                (const __attribute__((address_space(1))) unsigned int*)g,
                (__attribute__((address_space(3))) unsigned int*)l,
                16, 0, 0);
        }
    };

    issue_stage(0, 0);

    // runmin tracks min_p (||p||^2 - 2 x.p); ||x||^2 + clip folded in at end.
    float runmin[2][4] = {{1e30f, 1e30f, 1e30f, 1e30f},
                          {1e30f, 1e30f, 1e30f, 1e30f}};

    for (int s = 0; s < NSTAGES; ++s) {
        __syncthreads();   // stage-s LDS writes visible; prev readers done
        if (s + 1 < NSTAGES) issue_stage(s + 1, (s + 1) & 1);

        const ushort8* bbuf = &s_b[s & 1][0];
#pragma unroll
        for (int t = 0; t < 4; ++t) {
            ushort8 bfr[4];
#pragma unroll
            for (int c = 0; c < 4; ++c)
                bfr[c] = bbuf[(t * 4 + c) * 64 + lane];   // ds_read_b128
            f32x4 acc0 = {0.f, 0.f, 0.f, 0.f};
            f32x4 acc1 = {0.f, 0.f, 0.f, 0.f};
#pragma unroll
            for (int c = 0; c < 4; ++c) {
                BfCast cv; cv.u = bfr[c];
                acc0 = __builtin_amdgcn_mfma_f32_16x16x32_bf16(afrag[0][c], cv.b, acc0, 0, 0, 0);
                acc1 = __builtin_amdgcn_mfma_f32_16x16x32_bf16(afrag[1][c], cv.b, acc1, 0, 0, 0);
            }
            float pn = s_pn[s * STAGE_PTS + t * 16 + m];
#pragma unroll
            for (int r = 0; r < 4; ++r) {
                runmin[0][r] = fminf(runmin[0][r], fmaf(-2.f, acc0[r], pn));
                runmin[1][r] = fminf(runmin[1][r], fmaf(-2.f, acc1[r], pn));
            }
        }
    }

    // C/D layout: col = m, row_local = q*4 + r. Reduce min over the 16 cols.
    float br    = beta_raw[0];
    float beta  = log1pf(expf(br));
    float alpha = -beta * LOG1000F;
#pragma unroll
    for (int t = 0; t < 2; ++t) {
#pragma unroll
        for (int r = 0; r < 4; ++r) {
            float v = runmin[t][r];
            v = fminf(v, __shfl_xor(v, 1, 64));
            v = fminf(v, __shfl_xor(v, 2, 64));
            v = fminf(v, __shfl_xor(v, 4, 64));
            v = fminf(v, __shfl_xor(v, 8, 64));
            if (m == 0) {
                float xnv = s_xn[wave * 32 + t * 16 + q * 4 + r];
                float d2  = fmaxf(xnv + v, 0.f);
                float z   = (d2 + alpha) / beta;
                out[r0 + t * 16 + q * 4 + r] = 1.f / (1.f + expf(-z));
            }
        }
    }
}

extern "C" void kernel_launch(void* const* d_in, const int* in_sizes, int n_in,
                              void* d_out, int out_size, void* d_ws, size_t ws_size,
                              hipStream_t stream) {
    const float* x        = (const float*)d_in[0];
    const float* pts      = (const float*)d_in[1];
    const float* beta_raw = (const float*)d_in[2];
    float* out            = (float*)d_out;

    unsigned short* ptsbf = (unsigned short*)d_ws;                  // 512 KB
    float* pnorm = (float*)((char*)d_ws + (size_t)NPTS * DIMS * 2); // 8 KB

    prep_points_kernel<<<NPTS / 4, 256, 0, stream>>>(pts, ptsbf, pnorm);
    distnet_main_kernel<<<NROWS / 128, 256, 0, stream>>>(x, ptsbf, pnorm,
                                                         beta_raw, out);
}